// Round 16
// baseline (986.216 us; speedup 1.0000x reference)
//
#include <hip/hip_runtime.h>
#include <cstdint>
#include <cstddef>

#define NE   1024    // N_EMBD
#define DF   4096    // D_FF
#define KACT 1024    // K_ACTIVE
#define NTOK 16384   // B*S

typedef _Float16       f16x8  __attribute__((ext_vector_type(8)));
typedef unsigned short u16x8  __attribute__((ext_vector_type(8)));
typedef float          f32x4  __attribute__((ext_vector_type(4)));

#define MFMA16(a,b,c) __builtin_amdgcn_mfma_f32_16x16x32_f16(a,b,c,0,0,0)

// async global->LDS, 16B per lane; LDS dest = uniform base + lane*16 (linear)
#define GLD16(gp, lp) __builtin_amdgcn_global_load_lds( \
    (const __attribute__((address_space(1))) unsigned int*)(gp), \
    (__attribute__((address_space(3))) unsigned int*)(lp), 16, 0, 0)

// LDS tiles are [rows][32] f16 (64 B rows, 4x 16B chunks).
// r12-r15 conflict study: the 32x32 fragment shape pairs lanes i,i+32 on the
// SAME row (chunks 2s vs 2s+1) -> ~4 cy/read penalty invariant under any
// row-indexed swizzle (both lanes XOR identically). The 16x16 shape with
// sigma=(r>>1)&3 measured 0 conflicts (r10/r11). So: 16x16 frags everywhere,
// one sigma. global_load_lds fills linearly; the same involution
// pre-swizzles the per-lane GLOBAL source chunk (rule 21).
__device__ __forceinline__ int sigma(int row) {
    return (row >> 1) & 3;
}
__device__ __forceinline__ int swz(int row, int lk) {
    return row * 32 + ((((lk) >> 3) ^ sigma(row)) << 3);
}

// split fp32 -> hi fp16 + lo fp16 (residual)
__device__ __forceinline__ void cvt8(const float* f, f16x8& h, f16x8& l) {
    #pragma unroll
    for (int j = 0; j < 8; ++j) {
        _Float16 hh = (_Float16)f[j];
        h[j] = hh;
        l[j] = (_Float16)(f[j] - (float)hh);
    }
}

// ---------------------------------------------------------------------------
// Fused prep (1 launch): Wg->gh, Wu->uh, Wd->wdh (fp16), x->xh+xl (split).
// ---------------------------------------------------------------------------
__global__ __launch_bounds__(256) void k_prep(
    const float* __restrict__ Wg, const float* __restrict__ Wu,
    const float* __restrict__ Wd, const float* __restrict__ x,
    _Float16* __restrict__ gh, _Float16* __restrict__ uh,
    _Float16* __restrict__ wdh, _Float16* __restrict__ xh,
    _Float16* __restrict__ xl, int nw8, int nx8)
{
    int i = blockIdx.x * 256 + threadIdx.x;
    const float* s; _Float16* dh; _Float16* dl = nullptr; int j;
    if (i < nw8)            { s = Wg; dh = gh;  j = i; }
    else if (i < 2*nw8)     { s = Wu; dh = uh;  j = i - nw8; }
    else if (i < 3*nw8)     { s = Wd; dh = wdh; j = i - 2*nw8; }
    else if (i < 3*nw8+nx8) { s = x;  dh = xh;  dl = xl; j = i - 3*nw8; }
    else return;
    float4 a = ((const float4*)s)[2*j], b = ((const float4*)s)[2*j+1];
    float f[8] = {a.x,a.y,a.z,a.w,b.x,b.y,b.z,b.w};
    if (dl) {
        f16x8 hh, ll; cvt8(f, hh, ll);
        ((f16x8*)dh)[j] = hh; ((f16x8*)dl)[j] = ll;
    } else {
        f16x8 hh;
        #pragma unroll
        for (int q = 0; q < 8; ++q) hh[q] = (_Float16)f[q];
        ((f16x8*)dh)[j] = hh;
    }
}

// ---------------------------------------------------------------------------
// Up-projection via fp16x2 MFMA, 16x16x32 frags (0-conflict pattern),
// 128x128 tile (r15's ratio win kept):
// BM=128 tokens, BN=128 ff, BK=32. 4 waves (2x2); per-wave 64 tok x 64 ff
// for BOTH g and u. 64 MFMA16 + 16 ds_read_b128 + 8 GLD16 per wave/K-step.
// LDS per buf: XH/XL/GH/UH [128][32] = 32KB; x2 = 64KB (2 blk/CU).
//   acc = xh*W + xl*W (x split h+l, weights single fp16 — r11-verified).
// ---------------------------------------------------------------------------
#define OXH 0
#define OXL (128*32)
#define OGH (2*128*32)
#define OUH (3*128*32)
#define GUBUF (4*128*32)   // 16384 elements = 32KB

__global__ __launch_bounds__(256) void k_gemm_gu_mfma(
    const _Float16* __restrict__ xh, const _Float16* __restrict__ xl,
    const _Float16* __restrict__ gh, const _Float16* __restrict__ uh,
    _Float16* __restrict__ z, int nM)
{
    __shared__ _Float16 L[2 * GUBUF];
    const int t = threadIdx.x, lane = t & 63, wid = t >> 6;

    // 4x4 supertile swizzle for L2 locality
    int bid = blockIdx.x, mi, ni;
    if ((nM & 3) == 0) {
        int st = bid >> 4, lo = bid & 15, nstM = nM >> 2;
        mi = ((st % nstM) << 2) + (lo & 3);
        ni = ((st / nstM) << 2) + (lo >> 2);
    } else { mi = bid % nM; ni = bid / nM; }
    const int m0 = mi * 128, f0 = ni * 128;

    // ---- staging roles (per lane): linear LDS fill, pre-swizzled source ----
    const int rr = lane >> 2, slot = lane & 3;
    size_t xoff[2], goff[2];
    #pragma unroll
    for (int q = 0; q < 2; ++q) {
        int row = wid*32 + q*16 + rr;          // tile row 0..127
        int ss  = slot ^ sigma(row);
        xoff[q] = (size_t)(m0 + row) * (NE*2) + ss*16;
        goff[q] = (size_t)(f0 + row) * (NE*2) + ss*16;
    }
    const char* xhB = (const char*)xh;
    const char* xlB = (const char*)xl;
    const char* ghB = (const char*)gh;
    const char* uhB = (const char*)uh;

    const int wr = wid >> 1, wc = wid & 1;
    const int lrow = lane & 15, lk = (lane >> 4) * 8;   // 16x16 frag coords

    // hoisted, loop-invariant LDS read offsets
    int aoff[4], boff[4];
    #pragma unroll
    for (int mf = 0; mf < 4; ++mf)
        aoff[mf] = swz(wr*64 + mf*16 + lrow, lk);
    #pragma unroll
    for (int nf = 0; nf < 4; ++nf)
        boff[nf] = swz(wc*64 + nf*16 + lrow, lk);

    f32x4 accg[4][4] = {}, accu[4][4] = {};

    // stage K-step kt into buffer b (8 GLD16/lane)
    #define GU_STAGE(b, kt) do {                                              \
        _Float16* Lb = L + (b) * GUBUF;                                       \
        const size_t ka = (size_t)(kt) * 64;                                  \
        const char* xhK = xhB + ka;  const char* xlK = xlB + ka;              \
        const char* ghK = ghB + ka;  const char* uhK = uhB + ka;              \
        _Pragma("unroll")                                                     \
        for (int q = 0; q < 2; ++q) {                                         \
            GLD16(xhK + xoff[q], Lb + OXH + (wid*32 + q*16)*32);              \
            GLD16(xlK + xoff[q], Lb + OXL + (wid*32 + q*16)*32);              \
            GLD16(ghK + goff[q], Lb + OGH + (wid*32 + q*16)*32);              \
            GLD16(uhK + goff[q], Lb + OUH + (wid*32 + q*16)*32);              \
        }                                                                     \
    } while (0)

    GU_STAGE(0, 0);
    __syncthreads();

    int buf = 0;
    for (int kt = 0; kt < 32; ++kt) {
        if (kt + 1 < 32) GU_STAGE(buf ^ 1, kt + 1);
        const _Float16* Lb = &L[buf * GUBUF];
        f16x8 ah[4], al[4], bg[4], bu[4];
        #pragma unroll
        for (int mf = 0; mf < 4; ++mf) {
            ah[mf] = *(const f16x8*)&Lb[OXH + aoff[mf]];
            al[mf] = *(const f16x8*)&Lb[OXL + aoff[mf]];
        }
        #pragma unroll
        for (int nf = 0; nf < 4; ++nf) {
            bg[nf] = *(const f16x8*)&Lb[OGH + boff[nf]];
            bu[nf] = *(const f16x8*)&Lb[OUH + boff[nf]];
        }
        #pragma unroll
        for (int nf = 0; nf < 4; ++nf)
            #pragma unroll
            for (int mf = 0; mf < 4; ++mf) {
                accg[mf][nf] = MFMA16(ah[mf], bg[nf], accg[mf][nf]);
                accg[mf][nf] = MFMA16(al[mf], bg[nf], accg[mf][nf]);
                accu[mf][nf] = MFMA16(ah[mf], bu[nf], accu[mf][nf]);
                accu[mf][nf] = MFMA16(al[mf], bu[nf], accu[mf][nf]);
            }
        __syncthreads();
        buf ^= 1;
    }

    // epilogue: silu(g)*u with native exp; 16x16 C-layout store
    #pragma unroll
    for (int mf = 0; mf < 4; ++mf)
        #pragma unroll
        for (int nf = 0; nf < 4; ++nf)
            #pragma unroll
            for (int r = 0; r < 4; ++r) {
                int row = m0 + wr*64 + mf*16 + (lane>>4)*4 + r;
                int col = f0 + wc*64 + nf*16 + lrow;
                float g = accg[mf][nf][r], u = accu[mf][nf][r];
                float sg = g / (1.0f + __expf(-g));
                z[(size_t)row*DF + col] = (_Float16)(sg * u);
            }
    #undef GU_STAGE
}

// ---------------------------------------------------------------------------
// Exact per-token top-K mask on fp16 z: 2-pass radix select on the 15-bit
// magnitude key; stable ties by ascending index. Masks in place. (r10-verified)
// ---------------------------------------------------------------------------
__global__ __launch_bounds__(256) void k_topk_mask16(_Float16* __restrict__ z)
{
    __shared__ unsigned short zrow[DF];
    __shared__ unsigned hist[256];
    __shared__ int      cnts[256];
    __shared__ unsigned s_b1;
    __shared__ unsigned s_tkey;
    __shared__ int      s_remaining;

    const int t = threadIdx.x;
    unsigned short* zp = (unsigned short*)(z + (size_t)blockIdx.x * DF);

    for (int i = t; i < DF/8; i += 256) {
        ((ushort4*)zrow)[2*i]   = ((const ushort4*)zp)[2*i];
        ((ushort4*)zrow)[2*i+1] = ((const ushort4*)zp)[2*i+1];
    }
    if (t == 0) s_remaining = KACT;
    __syncthreads();

    hist[t] = 0u;
    __syncthreads();
    {
        const int base = t * 16;
        #pragma unroll
        for (int j = 0; j < 16; ++j) {
            unsigned key = zrow[base + j] & 0x7FFFu;
            atomicAdd(&hist[key >> 7], 1u);
        }
    }
    __syncthreads();
    if (t == 0) {
        int rem = s_remaining;
        int b = 255;
        for (; b > 0; --b) {
            int c = (int)hist[b];
            if (rem - c <= 0) break;
            rem -= c;
        }
        s_b1 = (unsigned)b;
        s_remaining = rem;
    }
    __syncthreads();

    const unsigned b1 = s_b1;
    hist[t] = 0u;
    __syncthreads();
    {
        const int base = t * 16;
        #pragma unroll
        for (int j = 0; j < 16; ++j) {
            unsigned key = zrow[base + j] & 0x7FFFu;
            if ((key >> 7) == b1) atomicAdd(&hist[key & 0x7Fu], 1u);
        }
    }
    __syncthreads();
    if (t == 0) {
        int rem = s_remaining;
        int b = 127;
        for (; b > 0; --b) {
            int c = (int)hist[b];
            if (rem - c <= 0) break;
            rem -= c;
        }
        s_tkey = (b1 << 7) | (unsigned)b;
        s_remaining = rem;
    }
    __syncthreads();

    const unsigned tkey = s_tkey;
    const int      E    = s_remaining;

    const int base = t * 16;
    int cnt = 0;
    #pragma unroll
    for (int j = 0; j < 16; ++j)
        if ((zrow[base + j] & 0x7FFFu) == tkey) cnt++;
    cnts[t] = cnt;
    __syncthreads();
    if (t == 0) {
        int run = 0;
        for (int i = 0; i < 256; ++i) { int c = cnts[i]; cnts[i] = run; run += c; }
    }
    __syncthreads();

    int rank = cnts[t];
    #pragma unroll
    for (int q = 0; q < 2; ++q) {
        u16x8 v;
        #pragma unroll
        for (int j = 0; j < 8; ++j) {
            int f = base + q*8 + j;
            unsigned short raw = zrow[f];
            unsigned key = raw & 0x7FFFu;
            bool sel;
            if (key > tkey)       sel = true;
            else if (key == tkey) { sel = (rank < E); rank++; }
            else                  sel = false;
            v[j] = sel ? raw : (unsigned short)0;
        }
        *(u16x8*)(zp + base + q*8) = v;
    }
}

// ---------------------------------------------------------------------------
// Down-projection, single fp16 16x16x32 MFMA, global_load_lds staged.
// (r11-verified structure; 0 conflicts measured at this pattern.)
// ---------------------------------------------------------------------------
#define OZH 0
#define OWH (128*32)
#define DNBUF (2*128*32)   // 8192 elements = 16KB

__global__ __launch_bounds__(256) void k_gemm_down_mfma(
    const _Float16* __restrict__ z, const _Float16* __restrict__ wdh,
    float* __restrict__ out, int tok0, int nM)
{
    __shared__ _Float16 L[2 * DNBUF];
    const int t = threadIdx.x, lane = t & 63, wid = t >> 6;

    int bid = blockIdx.x, mi, ni;
    if ((nM & 3) == 0) {
        int st = bid >> 4, lo = bid & 15, nstM = nM >> 2;
        mi = ((st % nstM) << 2) + (lo & 3);
        ni = ((st / nstM) << 2) + (lo >> 2);
    } else { mi = bid % nM; ni = bid / nM; }
    const int m0 = mi * 128, d0 = ni * 128;

    const int rr = lane >> 2, slot = lane & 3;
    size_t zoff[2], wof[2];
    #pragma unroll
    for (int q = 0; q < 2; ++q) {
        int row = wid*32 + q*16 + rr;
        int ss  = slot ^ sigma(row);
        zoff[q] = (size_t)(m0 + row) * (DF*2) + ss*16;
        wof[q]  = (size_t)(d0 + row) * (DF*2) + ss*16;
    }
    const char* zB = (const char*)z;
    const char* wB = (const char*)wdh;

    const int wr = wid >> 1, wc = wid & 1;
    const int lrow = lane & 15, lk = (lane >> 4) * 8;

    int aoff[4], boff[4];
    #pragma unroll
    for (int mf = 0; mf < 4; ++mf)
        aoff[mf] = swz(wr*64 + mf*16 + lrow, lk);
    #pragma unroll
    for (int nf = 0; nf < 4; ++nf)
        boff[nf] = swz(wc*64 + nf*16 + lrow, lk);

    f32x4 acc[4][4] = {};

    #define DN_STAGE(b, kt) do {                                              \
        _Float16* Lb = L + (b) * DNBUF;                                       \
        size_t ka = (size_t)(kt) * 64;                                        \
        _Pragma("unroll")                                                     \
        for (int q = 0; q < 2; ++q) {                                         \
            GLD16(zB + zoff[q] + ka, Lb + OZH + (wid*32 + q*16)*32);          \
            GLD16(wB + wof[q]  + ka, Lb + OWH + (wid*32 + q*16)*32);          \
        }                                                                     \
    } while (0)

    DN_STAGE(0, 0);
    __syncthreads();

    int buf = 0;
    for (int kt = 0; kt < DF/32; ++kt) {
        if (kt + 1 < DF/32) DN_STAGE(buf ^ 1, kt + 1);
        const _Float16* Lb = &L[buf * DNBUF];
        f16x8 ah[4], bh[4];
        #pragma unroll
        for (int mf = 0; mf < 4; ++mf)
            ah[mf] = *(const f16x8*)&Lb[OZH + aoff[mf]];
        #pragma unroll
        for (int nf = 0; nf < 4; ++nf)
            bh[nf] = *(const f16x8*)&Lb[OWH + boff[nf]];
        #pragma unroll
        for (int nf = 0; nf < 4; ++nf)
            #pragma unroll
            for (int mf = 0; mf < 4; ++mf)
                acc[mf][nf] = MFMA16(ah[mf], bh[nf], acc[mf][nf]);
        __syncthreads();
        buf ^= 1;
    }

    #pragma unroll
    for (int mf = 0; mf < 4; ++mf)
        #pragma unroll
        for (int nf = 0; nf < 4; ++nf)
            #pragma unroll
            for (int r = 0; r < 4; ++r) {
                int row = tok0 + m0 + wr*64 + mf*16 + (lane>>4)*4 + r;
                int col = d0 + wc*64 + nf*16 + lrow;
                out[(size_t)row*NE + col] = acc[mf][nf][r];
            }
    #undef DN_STAGE
}

// ---------------------------------------------------------------------------
extern "C" void kernel_launch(void* const* d_in, const int* in_sizes, int n_in,
                              void* d_out, int out_size, void* d_ws, size_t ws_size,
                              hipStream_t stream)
{
    const float* x  = (const float*)d_in[0];
    const float* Wg = (const float*)d_in[1];
    const float* Wu = (const float*)d_in[2];
    const float* Wd = (const float*)d_in[3];
    float* out = (float*)d_out;

    // fixed-size weights: gh/uh (DF*NE f16) + wdh (NE*DF f16) = 3 arrays
    const size_t wElems = (size_t)DF * NE;
    const size_t fixedBytes = wElems * 2 * 3;   // 25 MB

    // chunk tokens: need z fp16 (CT*DF*2) + xh/xl (CT*NE*2 each) + fixed
    int CT = NTOK;
    while (CT > 128 &&
           (size_t)CT*DF*2 + (size_t)CT*NE*4 + fixedBytes > ws_size) CT >>= 1;

    char* wsb = (char*)d_ws;
    _Float16* zbuf = (_Float16*)wsb;
    _Float16* xh   = (_Float16*)(wsb + (size_t)CT*DF*2);
    _Float16* xl   = xh + (size_t)CT*NE;
    _Float16* gh   = xl + (size_t)CT*NE;
    _Float16* uh   = gh + wElems;
    _Float16* wdh  = uh + wElems;

    const int nw8 = (int)(wElems / 8);

    for (int tok0 = 0; tok0 < NTOK; tok0 += CT) {
        int nM  = CT / 128;
        int nx8 = CT * NE / 8;
        int nPrep = 3*nw8 + nx8;
        k_prep<<<dim3((nPrep+255)/256), 256, 0, stream>>>(
            Wg, Wu, Wd, x + (size_t)tok0*NE, gh, uh, wdh, xh, xl, nw8, nx8);
        k_gemm_gu_mfma  <<<dim3(nM * (DF/128)), 256, 0, stream>>>(xh, xl, gh, uh, zbuf, nM);
        k_topk_mask16   <<<dim3(CT),            256, 0, stream>>>(zbuf);
        k_gemm_down_mfma<<<dim3(nM * (NE/128)), 256, 0, stream>>>(zbuf, wdh, out, tok0, nM);
    }
}

// Round 17
// 864.115 us; speedup vs baseline: 1.1413x; 1.1413x over previous
//
#include <hip/hip_runtime.h>
#include <cstdint>
#include <cstddef>

#define NE   1024    // N_EMBD
#define DF   4096    // D_FF
#define KACT 1024    // K_ACTIVE
#define NTOK 16384   // B*S

typedef _Float16       f16x8  __attribute__((ext_vector_type(8)));
typedef unsigned short u16x8  __attribute__((ext_vector_type(8)));
typedef float          f32x4  __attribute__((ext_vector_type(4)));

#define MFMA16(a,b,c) __builtin_amdgcn_mfma_f32_16x16x32_f16(a,b,c,0,0,0)

// async global->LDS, 16B per lane; LDS dest = uniform base + lane*16 (linear)
#define GLD16(gp, lp) __builtin_amdgcn_global_load_lds( \
    (const __attribute__((address_space(1))) unsigned int*)(gp), \
    (__attribute__((address_space(3))) unsigned int*)(lp), 16, 0, 0)

// LDS tiles are [rows][32] f16 (64 B rows, 4x 16B chunks).
// 16x16 frags + sigma=(r>>1)&3: measured 0 bank conflicts (r10/r11/r16).
// (32x32 frags carry an unfixable ~4cy/read same-row penalty — r12-r15.)
// global_load_lds fills linearly; the same involution pre-swizzles the
// per-lane GLOBAL source chunk (rule 21).
__device__ __forceinline__ int sigma(int row) {
    return (row >> 1) & 3;
}
__device__ __forceinline__ int swz(int row, int lk) {
    return row * 32 + ((((lk) >> 3) ^ sigma(row)) << 3);
}

// split fp32 -> hi fp16 + lo fp16 (residual)
__device__ __forceinline__ void cvt8(const float* f, f16x8& h, f16x8& l) {
    #pragma unroll
    for (int j = 0; j < 8; ++j) {
        _Float16 hh = (_Float16)f[j];
        h[j] = hh;
        l[j] = (_Float16)(f[j] - (float)hh);
    }
}

// ---------------------------------------------------------------------------
// Fused prep (1 launch): Wg->gh, Wu->uh, Wd->wdh (fp16), x->xh+xl (split).
// ---------------------------------------------------------------------------
__global__ __launch_bounds__(256) void k_prep(
    const float* __restrict__ Wg, const float* __restrict__ Wu,
    const float* __restrict__ Wd, const float* __restrict__ x,
    _Float16* __restrict__ gh, _Float16* __restrict__ uh,
    _Float16* __restrict__ wdh, _Float16* __restrict__ xh,
    _Float16* __restrict__ xl, int nw8, int nx8)
{
    int i = blockIdx.x * 256 + threadIdx.x;
    const float* s; _Float16* dh; _Float16* dl = nullptr; int j;
    if (i < nw8)            { s = Wg; dh = gh;  j = i; }
    else if (i < 2*nw8)     { s = Wu; dh = uh;  j = i - nw8; }
    else if (i < 3*nw8)     { s = Wd; dh = wdh; j = i - 2*nw8; }
    else if (i < 3*nw8+nx8) { s = x;  dh = xh;  dl = xl; j = i - 3*nw8; }
    else return;
    float4 a = ((const float4*)s)[2*j], b = ((const float4*)s)[2*j+1];
    float f[8] = {a.x,a.y,a.z,a.w,b.x,b.y,b.z,b.w};
    if (dl) {
        f16x8 hh, ll; cvt8(f, hh, ll);
        ((f16x8*)dh)[j] = hh; ((f16x8*)dl)[j] = ll;
    } else {
        f16x8 hh;
        #pragma unroll
        for (int q = 0; q < 8; ++q) hh[q] = (_Float16)f[q];
        ((f16x8*)dh)[j] = hh;
    }
}

// ---------------------------------------------------------------------------
// Up-projection via fp16x2 MFMA, 16x16x32 frags (0-conflict), 128x128 tile.
// r16 post-mortem: acc(128 f32) + 16 live operand frags (64 VGPR) crossed
// the 256-reg/wave cliff -> 1 wave/SIMD -> MfmaUtil 37%. Fix: B-frags
// loaded per-nf inside the loop (peak operands ~40 VGPR) and
// __launch_bounds__(256,2) pins 2 waves/EU.
// BM=128 tok, BN=128 ff, BK=32. 4 waves (2x2); per-wave 64x64 (g and u).
// LDS per buf: XH/XL/GH/UH [128][32] = 32KB; x2 = 64KB (2 blk/CU).
// ---------------------------------------------------------------------------
#define OXH 0
#define OXL (128*32)
#define OGH (2*128*32)
#define OUH (3*128*32)
#define GUBUF (4*128*32)   // 16384 elements = 32KB

__global__ __launch_bounds__(256, 2) void k_gemm_gu_mfma(
    const _Float16* __restrict__ xh, const _Float16* __restrict__ xl,
    const _Float16* __restrict__ gh, const _Float16* __restrict__ uh,
    _Float16* __restrict__ z, int nM)
{
    __shared__ _Float16 L[2 * GUBUF];
    const int t = threadIdx.x, lane = t & 63, wid = t >> 6;

    // 4x4 supertile swizzle for L2 locality
    int bid = blockIdx.x, mi, ni;
    if ((nM & 3) == 0) {
        int st = bid >> 4, lo = bid & 15, nstM = nM >> 2;
        mi = ((st % nstM) << 2) + (lo & 3);
        ni = ((st / nstM) << 2) + (lo >> 2);
    } else { mi = bid % nM; ni = bid / nM; }
    const int m0 = mi * 128, f0 = ni * 128;

    // ---- staging roles (per lane): linear LDS fill, pre-swizzled source ----
    const int rr = lane >> 2, slot = lane & 3;
    size_t xoff[2], goff[2];
    #pragma unroll
    for (int q = 0; q < 2; ++q) {
        int row = wid*32 + q*16 + rr;          // tile row 0..127
        int ss  = slot ^ sigma(row);
        xoff[q] = (size_t)(m0 + row) * (NE*2) + ss*16;
        goff[q] = (size_t)(f0 + row) * (NE*2) + ss*16;
    }
    const char* xhB = (const char*)xh;
    const char* xlB = (const char*)xl;
    const char* ghB = (const char*)gh;
    const char* uhB = (const char*)uh;

    const int wr = wid >> 1, wc = wid & 1;
    const int lrow = lane & 15, lk = (lane >> 4) * 8;   // 16x16 frag coords

    // hoisted, loop-invariant LDS read offsets
    int aoff[4], boff[4];
    #pragma unroll
    for (int mf = 0; mf < 4; ++mf)
        aoff[mf] = swz(wr*64 + mf*16 + lrow, lk);
    #pragma unroll
    for (int nf = 0; nf < 4; ++nf)
        boff[nf] = swz(wc*64 + nf*16 + lrow, lk);

    f32x4 accg[4][4] = {}, accu[4][4] = {};

    // stage K-step kt into buffer b (8 GLD16/lane)
    #define GU_STAGE(b, kt) do {                                              \
        _Float16* Lb = L + (b) * GUBUF;                                       \
        const size_t ka = (size_t)(kt) * 64;                                  \
        const char* xhK = xhB + ka;  const char* xlK = xlB + ka;              \
        const char* ghK = ghB + ka;  const char* uhK = uhB + ka;              \
        _Pragma("unroll")                                                     \
        for (int q = 0; q < 2; ++q) {                                         \
            GLD16(xhK + xoff[q], Lb + OXH + (wid*32 + q*16)*32);              \
            GLD16(xlK + xoff[q], Lb + OXL + (wid*32 + q*16)*32);              \
            GLD16(ghK + goff[q], Lb + OGH + (wid*32 + q*16)*32);              \
            GLD16(uhK + goff[q], Lb + OUH + (wid*32 + q*16)*32);              \
        }                                                                     \
    } while (0)

    GU_STAGE(0, 0);
    __syncthreads();

    int buf = 0;
    for (int kt = 0; kt < 32; ++kt) {
        if (kt + 1 < 32) GU_STAGE(buf ^ 1, kt + 1);
        const _Float16* Lb = &L[buf * GUBUF];
        f16x8 ah[4], al[4];
        #pragma unroll
        for (int mf = 0; mf < 4; ++mf) {
            ah[mf] = *(const f16x8*)&Lb[OXH + aoff[mf]];
            al[mf] = *(const f16x8*)&Lb[OXL + aoff[mf]];
        }
        #pragma unroll
        for (int nf = 0; nf < 4; ++nf) {
            f16x8 bg = *(const f16x8*)&Lb[OGH + boff[nf]];
            f16x8 bu = *(const f16x8*)&Lb[OUH + boff[nf]];
            #pragma unroll
            for (int mf = 0; mf < 4; ++mf) {
                accg[mf][nf] = MFMA16(ah[mf], bg, accg[mf][nf]);
                accg[mf][nf] = MFMA16(al[mf], bg, accg[mf][nf]);
                accu[mf][nf] = MFMA16(ah[mf], bu, accu[mf][nf]);
                accu[mf][nf] = MFMA16(al[mf], bu, accu[mf][nf]);
            }
        }
        __syncthreads();
        buf ^= 1;
    }

    // epilogue: silu(g)*u with native exp; 16x16 C-layout store
    #pragma unroll
    for (int mf = 0; mf < 4; ++mf)
        #pragma unroll
        for (int nf = 0; nf < 4; ++nf)
            #pragma unroll
            for (int r = 0; r < 4; ++r) {
                int row = m0 + wr*64 + mf*16 + (lane>>4)*4 + r;
                int col = f0 + wc*64 + nf*16 + lrow;
                float g = accg[mf][nf][r], u = accu[mf][nf][r];
                float sg = g / (1.0f + __expf(-g));
                z[(size_t)row*DF + col] = (_Float16)(sg * u);
            }
    #undef GU_STAGE
}

// ---------------------------------------------------------------------------
// Exact per-token top-K mask on fp16 z: 2-pass radix select on the 15-bit
// magnitude key; stable ties by ascending index. Masks in place. (r10-verified)
// ---------------------------------------------------------------------------
__global__ __launch_bounds__(256) void k_topk_mask16(_Float16* __restrict__ z)
{
    __shared__ unsigned short zrow[DF];
    __shared__ unsigned hist[256];
    __shared__ int      cnts[256];
    __shared__ unsigned s_b1;
    __shared__ unsigned s_tkey;
    __shared__ int      s_remaining;

    const int t = threadIdx.x;
    unsigned short* zp = (unsigned short*)(z + (size_t)blockIdx.x * DF);

    for (int i = t; i < DF/8; i += 256) {
        ((ushort4*)zrow)[2*i]   = ((const ushort4*)zp)[2*i];
        ((ushort4*)zrow)[2*i+1] = ((const ushort4*)zp)[2*i+1];
    }
    if (t == 0) s_remaining = KACT;
    __syncthreads();

    hist[t] = 0u;
    __syncthreads();
    {
        const int base = t * 16;
        #pragma unroll
        for (int j = 0; j < 16; ++j) {
            unsigned key = zrow[base + j] & 0x7FFFu;
            atomicAdd(&hist[key >> 7], 1u);
        }
    }
    __syncthreads();
    if (t == 0) {
        int rem = s_remaining;
        int b = 255;
        for (; b > 0; --b) {
            int c = (int)hist[b];
            if (rem - c <= 0) break;
            rem -= c;
        }
        s_b1 = (unsigned)b;
        s_remaining = rem;
    }
    __syncthreads();

    const unsigned b1 = s_b1;
    hist[t] = 0u;
    __syncthreads();
    {
        const int base = t * 16;
        #pragma unroll
        for (int j = 0; j < 16; ++j) {
            unsigned key = zrow[base + j] & 0x7FFFu;
            if ((key >> 7) == b1) atomicAdd(&hist[key & 0x7Fu], 1u);
        }
    }
    __syncthreads();
    if (t == 0) {
        int rem = s_remaining;
        int b = 127;
        for (; b > 0; --b) {
            int c = (int)hist[b];
            if (rem - c <= 0) break;
            rem -= c;
        }
        s_tkey = (b1 << 7) | (unsigned)b;
        s_remaining = rem;
    }
    __syncthreads();

    const unsigned tkey = s_tkey;
    const int      E    = s_remaining;

    const int base = t * 16;
    int cnt = 0;
    #pragma unroll
    for (int j = 0; j < 16; ++j)
        if ((zrow[base + j] & 0x7FFFu) == tkey) cnt++;
    cnts[t] = cnt;
    __syncthreads();
    if (t == 0) {
        int run = 0;
        for (int i = 0; i < 256; ++i) { int c = cnts[i]; cnts[i] = run; run += c; }
    }
    __syncthreads();

    int rank = cnts[t];
    #pragma unroll
    for (int q = 0; q < 2; ++q) {
        u16x8 v;
        #pragma unroll
        for (int j = 0; j < 8; ++j) {
            int f = base + q*8 + j;
            unsigned short raw = zrow[f];
            unsigned key = raw & 0x7FFFu;
            bool sel;
            if (key > tkey)       sel = true;
            else if (key == tkey) { sel = (rank < E); rank++; }
            else                  sel = false;
            v[j] = sel ? raw : (unsigned short)0;
        }
        *(u16x8*)(zp + base + q*8) = v;
    }
}

// ---------------------------------------------------------------------------
// Down-projection, single fp16 16x16x32 MFMA, global_load_lds staged.
// (r11-verified structure; 0 conflicts measured at this pattern.)
// ---------------------------------------------------------------------------
#define OZH 0
#define OWH (128*32)
#define DNBUF (2*128*32)   // 8192 elements = 16KB

__global__ __launch_bounds__(256) void k_gemm_down_mfma(
    const _Float16* __restrict__ z, const _Float16* __restrict__ wdh,
    float* __restrict__ out, int tok0, int nM)
{
    __shared__ _Float16 L[2 * DNBUF];
    const int t = threadIdx.x, lane = t & 63, wid = t >> 6;

    int bid = blockIdx.x, mi, ni;
    if ((nM & 3) == 0) {
        int st = bid >> 4, lo = bid & 15, nstM = nM >> 2;
        mi = ((st % nstM) << 2) + (lo & 3);
        ni = ((st / nstM) << 2) + (lo >> 2);
    } else { mi = bid % nM; ni = bid / nM; }
    const int m0 = mi * 128, d0 = ni * 128;

    const int rr = lane >> 2, slot = lane & 3;
    size_t zoff[2], wof[2];
    #pragma unroll
    for (int q = 0; q < 2; ++q) {
        int row = wid*32 + q*16 + rr;
        int ss  = slot ^ sigma(row);
        zoff[q] = (size_t)(m0 + row) * (DF*2) + ss*16;
        wof[q]  = (size_t)(d0 + row) * (DF*2) + ss*16;
    }
    const char* zB = (const char*)z;
    const char* wB = (const char*)wdh;

    const int wr = wid >> 1, wc = wid & 1;
    const int lrow = lane & 15, lk = (lane >> 4) * 8;

    int aoff[4], boff[4];
    #pragma unroll
    for (int mf = 0; mf < 4; ++mf)
        aoff[mf] = swz(wr*64 + mf*16 + lrow, lk);
    #pragma unroll
    for (int nf = 0; nf < 4; ++nf)
        boff[nf] = swz(wc*64 + nf*16 + lrow, lk);

    f32x4 acc[4][4] = {};

    #define DN_STAGE(b, kt) do {                                              \
        _Float16* Lb = L + (b) * DNBUF;                                       \
        size_t ka = (size_t)(kt) * 64;                                        \
        _Pragma("unroll")                                                     \
        for (int q = 0; q < 2; ++q) {                                         \
            GLD16(zB + zoff[q] + ka, Lb + OZH + (wid*32 + q*16)*32);          \
            GLD16(wB + wof[q]  + ka, Lb + OWH + (wid*32 + q*16)*32);          \
        }                                                                     \
    } while (0)

    DN_STAGE(0, 0);
    __syncthreads();

    int buf = 0;
    for (int kt = 0; kt < DF/32; ++kt) {
        if (kt + 1 < DF/32) DN_STAGE(buf ^ 1, kt + 1);
        const _Float16* Lb = &L[buf * DNBUF];
        f16x8 ah[4], bh[4];
        #pragma unroll
        for (int mf = 0; mf < 4; ++mf)
            ah[mf] = *(const f16x8*)&Lb[OZH + aoff[mf]];
        #pragma unroll
        for (int nf = 0; nf < 4; ++nf)
            bh[nf] = *(const f16x8*)&Lb[OWH + boff[nf]];
        #pragma unroll
        for (int nf = 0; nf < 4; ++nf)
            #pragma unroll
            for (int mf = 0; mf < 4; ++mf)
                acc[mf][nf] = MFMA16(ah[mf], bh[nf], acc[mf][nf]);
        __syncthreads();
        buf ^= 1;
    }

    #pragma unroll
    for (int mf = 0; mf < 4; ++mf)
        #pragma unroll
        for (int nf = 0; nf < 4; ++nf)
            #pragma unroll
            for (int r = 0; r < 4; ++r) {
                int row = tok0 + m0 + wr*64 + mf*16 + (lane>>4)*4 + r;
                int col = d0 + wc*64 + nf*16 + lrow;
                out[(size_t)row*NE + col] = acc[mf][nf][r];
            }
    #undef DN_STAGE
}

// ---------------------------------------------------------------------------
extern "C" void kernel_launch(void* const* d_in, const int* in_sizes, int n_in,
                              void* d_out, int out_size, void* d_ws, size_t ws_size,
                              hipStream_t stream)
{
    const float* x  = (const float*)d_in[0];
    const float* Wg = (const float*)d_in[1];
    const float* Wu = (const float*)d_in[2];
    const float* Wd = (const float*)d_in[3];
    float* out = (float*)d_out;

    // fixed-size weights: gh/uh (DF*NE f16) + wdh (NE*DF f16) = 3 arrays
    const size_t wElems = (size_t)DF * NE;
    const size_t fixedBytes = wElems * 2 * 3;   // 25 MB

    // chunk tokens: need z fp16 (CT*DF*2) + xh/xl (CT*NE*2 each) + fixed
    int CT = NTOK;
    while (CT > 128 &&
           (size_t)CT*DF*2 + (size_t)CT*NE*4 + fixedBytes > ws_size) CT >>= 1;

    char* wsb = (char*)d_ws;
    _Float16* zbuf = (_Float16*)wsb;
    _Float16* xh   = (_Float16*)(wsb + (size_t)CT*DF*2);
    _Float16* xl   = xh + (size_t)CT*NE;
    _Float16* gh   = xl + (size_t)CT*NE;
    _Float16* uh   = gh + wElems;
    _Float16* wdh  = uh + wElems;

    const int nw8 = (int)(wElems / 8);

    for (int tok0 = 0; tok0 < NTOK; tok0 += CT) {
        int nM  = CT / 128;
        int nx8 = CT * NE / 8;
        int nPrep = 3*nw8 + nx8;
        k_prep<<<dim3((nPrep+255)/256), 256, 0, stream>>>(
            Wg, Wu, Wd, x + (size_t)tok0*NE, gh, uh, wdh, xh, xl, nw8, nx8);
        k_gemm_gu_mfma  <<<dim3(nM * (DF/128)), 256, 0, stream>>>(xh, xl, gh, uh, zbuf, nM);
        k_topk_mask16   <<<dim3(CT),            256, 0, stream>>>(zbuf);
        k_gemm_down_mfma<<<dim3(nM * (NE/128)), 256, 0, stream>>>(zbuf, wdh, out, tok0, nM);
    }
}

// Round 19
// 816.872 us; speedup vs baseline: 1.2073x; 1.0578x over previous
//
#include <hip/hip_runtime.h>
#include <cstdint>
#include <cstddef>

#define NE   1024    // N_EMBD
#define DF   4096    // D_FF
#define KACT 1024    // K_ACTIVE
#define NTOK 16384   // B*S

typedef _Float16       f16x8  __attribute__((ext_vector_type(8)));
typedef unsigned short u16x8  __attribute__((ext_vector_type(8)));
typedef float          f32x4  __attribute__((ext_vector_type(4)));

#define MFMA16(a,b,c) __builtin_amdgcn_mfma_f32_16x16x32_f16(a,b,c,0,0,0)

// async global->LDS, 16B per lane; LDS dest = uniform base + lane*16 (linear)
#define GLD16(gp, lp) __builtin_amdgcn_global_load_lds( \
    (const __attribute__((address_space(1))) unsigned int*)(gp), \
    (__attribute__((address_space(3))) unsigned int*)(lp), 16, 0, 0)

// LDS tiles are [rows][32] f16 (64 B rows, 4x 16B chunks).
// 16x16 frags + sigma=(r>>1)&3: measured 0 bank conflicts (r10/r11/r16/r17).
// (32x32 frags carry an unfixable ~4cy/read same-row penalty — r12-r15.)
// global_load_lds fills linearly; the same involution pre-swizzles the
// per-lane GLOBAL source chunk (rule 21).
__device__ __forceinline__ int sigma(int row) {
    return (row >> 1) & 3;
}
__device__ __forceinline__ int swz(int row, int lk) {
    return row * 32 + ((((lk) >> 3) ^ sigma(row)) << 3);
}

// split fp32 -> hi fp16 + lo fp16 (residual)
__device__ __forceinline__ void cvt8(const float* f, f16x8& h, f16x8& l) {
    #pragma unroll
    for (int j = 0; j < 8; ++j) {
        _Float16 hh = (_Float16)f[j];
        h[j] = hh;
        l[j] = (_Float16)(f[j] - (float)hh);
    }
}

// ---------------------------------------------------------------------------
// Fused prep (1 launch): Wg->gh, Wu->uh, Wd->wdh (fp16), x->xh+xl (split).
// ---------------------------------------------------------------------------
__global__ __launch_bounds__(256) void k_prep(
    const float* __restrict__ Wg, const float* __restrict__ Wu,
    const float* __restrict__ Wd, const float* __restrict__ x,
    _Float16* __restrict__ gh, _Float16* __restrict__ uh,
    _Float16* __restrict__ wdh, _Float16* __restrict__ xh,
    _Float16* __restrict__ xl, int nw8, int nx8)
{
    int i = blockIdx.x * 256 + threadIdx.x;
    const float* s; _Float16* dh; _Float16* dl = nullptr; int j;
    if (i < nw8)            { s = Wg; dh = gh;  j = i; }
    else if (i < 2*nw8)     { s = Wu; dh = uh;  j = i - nw8; }
    else if (i < 3*nw8)     { s = Wd; dh = wdh; j = i - 2*nw8; }
    else if (i < 3*nw8+nx8) { s = x;  dh = xh;  dl = xl; j = i - 3*nw8; }
    else return;
    float4 a = ((const float4*)s)[2*j], b = ((const float4*)s)[2*j+1];
    float f[8] = {a.x,a.y,a.z,a.w,b.x,b.y,b.z,b.w};
    if (dl) {
        f16x8 hh, ll; cvt8(f, hh, ll);
        ((f16x8*)dh)[j] = hh; ((f16x8*)dl)[j] = ll;
    } else {
        f16x8 hh;
        #pragma unroll
        for (int q = 0; q < 8; ++q) hh[q] = (_Float16)f[q];
        ((f16x8*)dh)[j] = hh;
    }
}

// ---------------------------------------------------------------------------
// Up-projection via fp16x2 MFMA, 16x16x32 frags (0-conflict), 128x128 tile.
// (r17-verified: 457us, MfmaUtil 59%, 0 conflicts, VGPR 104, 2 waves/EU.)
// ---------------------------------------------------------------------------
#define OXH 0
#define OXL (128*32)
#define OGH (2*128*32)
#define OUH (3*128*32)
#define GUBUF (4*128*32)   // 16384 elements = 32KB

__global__ __launch_bounds__(256, 2) void k_gemm_gu_mfma(
    const _Float16* __restrict__ xh, const _Float16* __restrict__ xl,
    const _Float16* __restrict__ gh, const _Float16* __restrict__ uh,
    _Float16* __restrict__ z, int nM)
{
    __shared__ _Float16 L[2 * GUBUF];
    const int t = threadIdx.x, lane = t & 63, wid = t >> 6;

    // 4x4 supertile swizzle for L2 locality
    int bid = blockIdx.x, mi, ni;
    if ((nM & 3) == 0) {
        int st = bid >> 4, lo = bid & 15, nstM = nM >> 2;
        mi = ((st % nstM) << 2) + (lo & 3);
        ni = ((st / nstM) << 2) + (lo >> 2);
    } else { mi = bid % nM; ni = bid / nM; }
    const int m0 = mi * 128, f0 = ni * 128;

    // ---- staging roles (per lane): linear LDS fill, pre-swizzled source ----
    const int rr = lane >> 2, slot = lane & 3;
    size_t xoff[2], goff[2];
    #pragma unroll
    for (int q = 0; q < 2; ++q) {
        int row = wid*32 + q*16 + rr;          // tile row 0..127
        int ss  = slot ^ sigma(row);
        xoff[q] = (size_t)(m0 + row) * (NE*2) + ss*16;
        goff[q] = (size_t)(f0 + row) * (NE*2) + ss*16;
    }
    const char* xhB = (const char*)xh;
    const char* xlB = (const char*)xl;
    const char* ghB = (const char*)gh;
    const char* uhB = (const char*)uh;

    const int wr = wid >> 1, wc = wid & 1;
    const int lrow = lane & 15, lk = (lane >> 4) * 8;   // 16x16 frag coords

    // hoisted, loop-invariant LDS read offsets
    int aoff[4], boff[4];
    #pragma unroll
    for (int mf = 0; mf < 4; ++mf)
        aoff[mf] = swz(wr*64 + mf*16 + lrow, lk);
    #pragma unroll
    for (int nf = 0; nf < 4; ++nf)
        boff[nf] = swz(wc*64 + nf*16 + lrow, lk);

    f32x4 accg[4][4] = {}, accu[4][4] = {};

    // stage K-step kt into buffer b (8 GLD16/lane)
    #define GU_STAGE(b, kt) do {                                              \
        _Float16* Lb = L + (b) * GUBUF;                                       \
        const size_t ka = (size_t)(kt) * 64;                                  \
        const char* xhK = xhB + ka;  const char* xlK = xlB + ka;              \
        const char* ghK = ghB + ka;  const char* uhK = uhB + ka;              \
        _Pragma("unroll")                                                     \
        for (int q = 0; q < 2; ++q) {                                         \
            GLD16(xhK + xoff[q], Lb + OXH + (wid*32 + q*16)*32);              \
            GLD16(xlK + xoff[q], Lb + OXL + (wid*32 + q*16)*32);              \
            GLD16(ghK + goff[q], Lb + OGH + (wid*32 + q*16)*32);              \
            GLD16(uhK + goff[q], Lb + OUH + (wid*32 + q*16)*32);              \
        }                                                                     \
    } while (0)

    GU_STAGE(0, 0);
    __syncthreads();

    int buf = 0;
    for (int kt = 0; kt < 32; ++kt) {
        if (kt + 1 < 32) GU_STAGE(buf ^ 1, kt + 1);
        const _Float16* Lb = &L[buf * GUBUF];
        f16x8 ah[4], al[4];
        #pragma unroll
        for (int mf = 0; mf < 4; ++mf) {
            ah[mf] = *(const f16x8*)&Lb[OXH + aoff[mf]];
            al[mf] = *(const f16x8*)&Lb[OXL + aoff[mf]];
        }
        #pragma unroll
        for (int nf = 0; nf < 4; ++nf) {
            f16x8 bg = *(const f16x8*)&Lb[OGH + boff[nf]];
            f16x8 bu = *(const f16x8*)&Lb[OUH + boff[nf]];
            #pragma unroll
            for (int mf = 0; mf < 4; ++mf) {
                accg[mf][nf] = MFMA16(ah[mf], bg, accg[mf][nf]);
                accg[mf][nf] = MFMA16(al[mf], bg, accg[mf][nf]);
                accu[mf][nf] = MFMA16(ah[mf], bu, accu[mf][nf]);
                accu[mf][nf] = MFMA16(al[mf], bu, accu[mf][nf]);
            }
        }
        __syncthreads();
        buf ^= 1;
    }

    // epilogue: silu(g)*u with native exp; 16x16 C-layout store
    #pragma unroll
    for (int mf = 0; mf < 4; ++mf)
        #pragma unroll
        for (int nf = 0; nf < 4; ++nf)
            #pragma unroll
            for (int r = 0; r < 4; ++r) {
                int row = m0 + wr*64 + mf*16 + (lane>>4)*4 + r;
                int col = f0 + wc*64 + nf*16 + lrow;
                float g = accg[mf][nf][r], u = accu[mf][nf][r];
                float sg = g / (1.0f + __expf(-g));
                z[(size_t)row*DF + col] = (_Float16)(sg * u);
            }
    #undef GU_STAGE
}

// ---------------------------------------------------------------------------
// Exact per-token top-K mask on fp16 z: 2-pass radix select on the 15-bit
// magnitude key; stable ties by ascending index. Masks in place. (r10-verified)
// ---------------------------------------------------------------------------
__global__ __launch_bounds__(256) void k_topk_mask16(_Float16* __restrict__ z)
{
    __shared__ unsigned short zrow[DF];
    __shared__ unsigned hist[256];
    __shared__ int      cnts[256];
    __shared__ unsigned s_b1;
    __shared__ unsigned s_tkey;
    __shared__ int      s_remaining;

    const int t = threadIdx.x;
    unsigned short* zp = (unsigned short*)(z + (size_t)blockIdx.x * DF);

    for (int i = t; i < DF/8; i += 256) {
        ((ushort4*)zrow)[2*i]   = ((const ushort4*)zp)[2*i];
        ((ushort4*)zrow)[2*i+1] = ((const ushort4*)zp)[2*i+1];
    }
    if (t == 0) s_remaining = KACT;
    __syncthreads();

    hist[t] = 0u;
    __syncthreads();
    {
        const int base = t * 16;
        #pragma unroll
        for (int j = 0; j < 16; ++j) {
            unsigned key = zrow[base + j] & 0x7FFFu;
            atomicAdd(&hist[key >> 7], 1u);
        }
    }
    __syncthreads();
    if (t == 0) {
        int rem = s_remaining;
        int b = 255;
        for (; b > 0; --b) {
            int c = (int)hist[b];
            if (rem - c <= 0) break;
            rem -= c;
        }
        s_b1 = (unsigned)b;
        s_remaining = rem;
    }
    __syncthreads();

    const unsigned b1 = s_b1;
    hist[t] = 0u;
    __syncthreads();
    {
        const int base = t * 16;
        #pragma unroll
        for (int j = 0; j < 16; ++j) {
            unsigned key = zrow[base + j] & 0x7FFFu;
            if ((key >> 7) == b1) atomicAdd(&hist[key & 0x7Fu], 1u);
        }
    }
    __syncthreads();
    if (t == 0) {
        int rem = s_remaining;
        int b = 127;
        for (; b > 0; --b) {
            int c = (int)hist[b];
            if (rem - c <= 0) break;
            rem -= c;
        }
        s_tkey = (b1 << 7) | (unsigned)b;
        s_remaining = rem;
    }
    __syncthreads();

    const unsigned tkey = s_tkey;
    const int      E    = s_remaining;

    const int base = t * 16;
    int cnt = 0;
    #pragma unroll
    for (int j = 0; j < 16; ++j)
        if ((zrow[base + j] & 0x7FFFu) == tkey) cnt++;
    cnts[t] = cnt;
    __syncthreads();
    if (t == 0) {
        int run = 0;
        for (int i = 0; i < 256; ++i) { int c = cnts[i]; cnts[i] = run; run += c; }
    }
    __syncthreads();

    int rank = cnts[t];
    #pragma unroll
    for (int q = 0; q < 2; ++q) {
        u16x8 v;
        #pragma unroll
        for (int j = 0; j < 8; ++j) {
            int f = base + q*8 + j;
            unsigned short raw = zrow[f];
            unsigned key = raw & 0x7FFFu;
            bool sel;
            if (key > tkey)       sel = true;
            else if (key == tkey) { sel = (rank < E); rank++; }
            else                  sel = false;
            v[j] = sel ? raw : (unsigned short)0;
        }
        *(u16x8*)(zp + base + q*8) = v;
    }
}

// ---------------------------------------------------------------------------
// Down-projection, fp16 16x16x32 MFMA, BK=64 (r18): two 32-wide K-subtiles
// per LDS buffer -> 32 MFMA + 16 ds_read + 8 GLD16 per wave/K-step, 64
// iterations (was 16 MFMA / 128 iters: barrier-bound at ~78cy/phase).
// LDS per buf: Z[2][128][32] + W[2][128][32] = 32KB; x2 = 64KB (2 blk/CU).
// Accumulation order unchanged (ascending k) -> bit-identical output.
// ---------------------------------------------------------------------------
#define OZH 0
#define OWH (2*128*32)
#define DNBUF (4*128*32)   // 16384 elements = 32KB

__global__ __launch_bounds__(256, 2) void k_gemm_down_mfma(
    const _Float16* __restrict__ z, const _Float16* __restrict__ wdh,
    float* __restrict__ out, int tok0, int nM)
{
    __shared__ _Float16 L[2 * DNBUF];
    const int t = threadIdx.x, lane = t & 63, wid = t >> 6;

    int bid = blockIdx.x, mi, ni;
    if ((nM & 3) == 0) {
        int st = bid >> 4, lo = bid & 15, nstM = nM >> 2;
        mi = ((st % nstM) << 2) + (lo & 3);
        ni = ((st / nstM) << 2) + (lo >> 2);
    } else { mi = bid % nM; ni = bid / nM; }
    const int m0 = mi * 128, d0 = ni * 128;

    const int rr = lane >> 2, slot = lane & 3;
    size_t zoff[2], wof[2];
    #pragma unroll
    for (int q = 0; q < 2; ++q) {
        int row = wid*32 + q*16 + rr;
        int ss  = slot ^ sigma(row);
        zoff[q] = (size_t)(m0 + row) * (DF*2) + ss*16;
        wof[q]  = (size_t)(d0 + row) * (DF*2) + ss*16;
    }
    const char* zB = (const char*)z;
    const char* wB = (const char*)wdh;

    const int wr = wid >> 1, wc = wid & 1;
    const int lrow = lane & 15, lk = (lane >> 4) * 8;

    int aoff[4], boff[4];
    #pragma unroll
    for (int mf = 0; mf < 4; ++mf)
        aoff[mf] = swz(wr*64 + mf*16 + lrow, lk);
    #pragma unroll
    for (int nf = 0; nf < 4; ++nf)
        boff[nf] = swz(wc*64 + nf*16 + lrow, lk);

    f32x4 acc[4][4] = {};

    // stage K-step kt (64 k-elems = 128 B/row; 2 subtiles) into buffer b
    #define DN_STAGE(b, kt) do {                                              \
        _Float16* Lb = L + (b) * DNBUF;                                       \
        const size_t ka = (size_t)(kt) * 128;                                 \
        _Pragma("unroll")                                                     \
        for (int q = 0; q < 2; ++q)                                           \
            _Pragma("unroll")                                                 \
            for (int s = 0; s < 2; ++s) {                                     \
                GLD16(zB + zoff[q] + ka + s*64,                               \
                      Lb + OZH + s*(128*32) + (wid*32 + q*16)*32);            \
                GLD16(wB + wof[q] + ka + s*64,                                \
                      Lb + OWH + s*(128*32) + (wid*32 + q*16)*32);            \
            }                                                                 \
    } while (0)

    DN_STAGE(0, 0);
    __syncthreads();

    int buf = 0;
    for (int kt = 0; kt < DF/64; ++kt) {
        if (kt + 1 < DF/64) DN_STAGE(buf ^ 1, kt + 1);
        const _Float16* Lb = &L[buf * DNBUF];
        #pragma unroll
        for (int s = 0; s < 2; ++s) {
            f16x8 ah[4];
            #pragma unroll
            for (int mf = 0; mf < 4; ++mf)
                ah[mf] = *(const f16x8*)&Lb[OZH + s*(128*32) + aoff[mf]];
            #pragma unroll
            for (int nf = 0; nf < 4; ++nf) {
                f16x8 bh = *(const f16x8*)&Lb[OWH + s*(128*32) + boff[nf]];
                #pragma unroll
                for (int mf = 0; mf < 4; ++mf)
                    acc[mf][nf] = MFMA16(ah[mf], bh, acc[mf][nf]);
            }
        }
        __syncthreads();
        buf ^= 1;
    }

    #pragma unroll
    for (int mf = 0; mf < 4; ++mf)
        #pragma unroll
        for (int nf = 0; nf < 4; ++nf)
            #pragma unroll
            for (int r = 0; r < 4; ++r) {
                int row = tok0 + m0 + wr*64 + mf*16 + (lane>>4)*4 + r;
                int col = d0 + wc*64 + nf*16 + lrow;
                out[(size_t)row*NE + col] = acc[mf][nf][r];
            }
    #undef DN_STAGE
}

// ---------------------------------------------------------------------------
extern "C" void kernel_launch(void* const* d_in, const int* in_sizes, int n_in,
                              void* d_out, int out_size, void* d_ws, size_t ws_size,
                              hipStream_t stream)
{
    const float* x  = (const float*)d_in[0];
    const float* Wg = (const float*)d_in[1];
    const float* Wu = (const float*)d_in[2];
    const float* Wd = (const float*)d_in[3];
    float* out = (float*)d_out;

    // fixed-size weights: gh/uh (DF*NE f16) + wdh (NE*DF f16) = 3 arrays
    const size_t wElems = (size_t)DF * NE;
    const size_t fixedBytes = wElems * 2 * 3;   // 25 MB

    // chunk tokens: need z fp16 (CT*DF*2) + xh/xl (CT*NE*2 each) + fixed
    int CT = NTOK;
    while (CT > 128 &&
           (size_t)CT*DF*2 + (size_t)CT*NE*4 + fixedBytes > ws_size) CT >>= 1;

    char* wsb = (char*)d_ws;
    _Float16* zbuf = (_Float16*)wsb;
    _Float16* xh   = (_Float16*)(wsb + (size_t)CT*DF*2);
    _Float16* xl   = xh + (size_t)CT*NE;
    _Float16* gh   = xl + (size_t)CT*NE;
    _Float16* uh   = gh + wElems;
    _Float16* wdh  = uh + wElems;

    const int nw8 = (int)(wElems / 8);

    for (int tok0 = 0; tok0 < NTOK; tok0 += CT) {
        int nM  = CT / 128;
        int nx8 = CT * NE / 8;
        int nPrep = 3*nw8 + nx8;
        k_prep<<<dim3((nPrep+255)/256), 256, 0, stream>>>(
            Wg, Wu, Wd, x + (size_t)tok0*NE, gh, uh, wdh, xh, xl, nw8, nx8);
        k_gemm_gu_mfma  <<<dim3(nM * (DF/128)), 256, 0, stream>>>(xh, xl, gh, uh, zbuf, nM);
        k_topk_mask16   <<<dim3(CT),            256, 0, stream>>>(zbuf);
        k_gemm_down_mfma<<<dim3(nM * (NE/128)), 256, 0, stream>>>(zbuf, wdh, out, tok0, nM);
    }
}